// Round 10
// baseline (711.850 us; speedup 1.0000x reference)
//
#include <hip/hip_runtime.h>

#define GN    128
#define GBIG  1.0e5f
#define NITER 128

// Padded layout: x pitch 128, y and z padded to 130 with BIG boundary planes.
#define PPY     130
#define PITCH_Y 128
#define PITCH_Z (128 * 130)
#define PADDED_TOTAL (130 * 130 * 128)

// Wave-tile lattice: each WAVE owns a 128 x 2 x 2 tile.  64 x 64 tiles.
// Block = 4 waves arranged 2x2 (y,z); grid 32 x 32 blocks = 1024 blocks.
#define NTY  64
#define NTZ  64
#define NTILE (NTY * NTZ)

typedef float fx4 __attribute__((ext_vector_type(4)));
typedef int   ix4 __attribute__((ext_vector_type(4)));

// ---------------------------------------------------------------------------
// init: padded uA, uB, fP + per-tile inbox lines (64B each).
// inbox[t][0..3] = iter published by the {-y,+y,-z,+z} producer of tile t.
// Missing producer => NITER (satisfies any target).
// ---------------------------------------------------------------------------
__global__ __launch_bounds__(256) void eik_init(const float* __restrict__ u0,
                                                const float* __restrict__ f,
                                                float* __restrict__ uA,
                                                float* __restrict__ uB,
                                                float* __restrict__ fP,
                                                int* __restrict__ inbox) {
    const int i = blockIdx.x * 256 + threadIdx.x;
    if (i < NTILE * 16) {
        const int t = i >> 4, d = i & 15;
        const int ly = t & 63, lz = t >> 6;
        int v = 0;
        if ((d == 0 && ly == 0) || (d == 1 && ly == NTY - 1) ||
            (d == 2 && lz == 0) || (d == 3 && lz == NTZ - 1))
            v = NITER;
        inbox[i] = v;
    }
    if (i >= PADDED_TOTAL) return;
    const int x = i & 127;
    const int r = i >> 7;          // r = z*130 + y
    const int y = r % 130;
    const int z = r / 130;
    float uv = GBIG, fv = 0.0f;
    if (y >= 1 && y <= GN && z >= 1 && z <= GN) {
        const int src = ((z - 1) * GN + (y - 1)) * GN + x;
        uv = u0[src];
        fv = f[src];
    }
    uA[i] = uv;
    uB[i] = uv;
    fP[i] = fv;
}

// fh2 = fh*fh hoisted (loop-invariant per cell).
__device__ __forceinline__ float eik_solve(float ax, float ay, float az,
                                           float fh, float fh2, float uc) {
    const float a1 = fminf(fminf(ax, ay), az);
    const float a3 = fmaxf(fmaxf(ax, ay), az);
    const float a2 = fmaxf(fminf(fmaxf(ax, ay), az), fminf(ax, ay));
    const float x1 = a1 + fh;
    const float d12 = a1 - a2;
    const float disc2 = fh2 + fh2 - d12 * d12;
    const float x2 = 0.5f * (a1 + a2 + sqrtf(fmaxf(disc2, 0.0f)));
    const float s = a1 + a2 + a3;
    const float q = a1 * a1 + a2 * a2 + a3 * a3;
    const float disc3 = s * s - 3.0f * (q - fh2);
    const float x3 = (s + sqrtf(fmaxf(disc3, 0.0f))) * (1.0f / 3.0f);
    const float xv = (x1 <= a2) ? x1 : ((x2 <= a3) ? x2 : x3);
    return fminf(uc, xv);
}

// FLAT addressing throughout (saddr "s"-form miscompiled in round 7).
__device__ __forceinline__ void pubp(int* p, int val) {
    asm volatile("global_store_dword %0, %1, off sc1"
                 :: "v"(p), "v"(val) : "memory");
}
__device__ __forceinline__ void stS(float* p, fx4 v) {
    asm volatile("global_store_dwordx4 %0, %1, off sc1"
                 :: "v"(p), "v"(v) : "memory");
}

// ---------------------------------------------------------------------------
// persistent kernel, plain launch (graph-capturable).  1024 blocks x 4
// independent waves = 4096 wave-tiles of 128x2x2, no __syncthreads (R8 base,
// proven absmax 0.5).  R10 changes, per the VALUBusy census:
//  (1) SPIN DIET: poll cadence s_sleep(16) (~0.43us); s_sleep(64) (~1.7us)
//      when >2 rounds behind (pre-wavefront tiles).  R8/R9's s_sleep(1) gave
//      ~0.3us poll cadence -> ~10 poll iters x ~15 issue slots per wait per
//      wave per round = the unexplained 2us of VALUBusy (spin saturation).
//  (2) VALU DIET: loop unrolled by 2 on buffer parity; all 12 flat halo /
//      store pointers hoisted out of the loop (zero per-round address math
//      and zero per-round buffer selects).  Change-tracking (R9) dropped —
//      it never engaged (values keep refining; FETCH/VALU unchanged).
//
// Protocol (unchanged from R8): inbox slot >= i-1 gates both RAW and WAR of
// the ping-pong buffers.  flag=i implies round-i stores drained (vmcnt0
// before pub) and round-i reads done (loads waitcnt'd before compute which
// precedes stores).  Per-face direction culling: skip waiting on faces whose
// adjacent cells are all inactive (d > i) — act-culled cells are never
// stored, so nothing stale can be read.
// ---------------------------------------------------------------------------
__global__ __launch_bounds__(256, 4) void eik_persist(float* __restrict__ uA,
                                                      float* __restrict__ uB,
                                                      const float* __restrict__ fP,
                                                      float* __restrict__ out,
                                                      int* __restrict__ inbox) {
    const int tid  = threadIdx.x;      // 0..255
    const int w    = tid >> 6;         // wave 0..3
    const int lane = tid & 63;
    const int r    = lane >> 5;        // row within tile (0/1)
    const int sub  = lane & 31;        // x-group
    const int x0   = sub * 4;

    // wave-tile coords: block = 2x2 waves
    const int ly = blockIdx.y * 2 + (w & 1);   // 0..63
    const int lz = blockIdx.z * 2 + (w >> 1);  // 0..63
    const int gy0 = ly * 2;                    // rows gy0, gy0+1
    const int gz0 = lz * 2;                    // planes gz0, gz0+1
    const int gy  = gy0 + r;

    // per-cell act distances (exact active-set cull)
    const int dxm = (x0 <= 64 && 64 <= x0 + 3) ? 0
                                               : min(abs(x0 - 64), abs(x0 + 3 - 64));
    const int dy = abs(gy - 64);
    const int d0 = dxm + dy + abs(gz0 - 64);
    const int d1 = dxm + dy + abs(gz0 + 1 - 64);
    const int dmin01 = min(d0, d1);

    // tile/face distances
    const int dymin = (gy0 > 64) ? (gy0 - 64) : ((gy0 + 1 < 64) ? (64 - (gy0 + 1)) : 0);
    const int dzmin = (gz0 > 64) ? (gz0 - 64) : ((gz0 + 1 < 64) ? (64 - (gz0 + 1)) : 0);
    const int start = max(1, dymin + dzmin);
    const int dYm = abs(gy0 - 64) + dzmin;       // face row gy0      (slot 0)
    const int dYp = abs(gy0 + 1 - 64) + dzmin;   // face row gy0+1    (slot 1)
    const int dZm = abs(gz0 - 64) + dymin;       // face plane gz0    (slot 2)
    const int dZp = abs(gz0 + 1 - 64) + dymin;   // face plane gz0+1  (slot 3)

    const int idx = lz * NTY + ly;
    int* inb = inbox + idx * 16;                 // own 64B line
    int* pYp = inbox + (idx + 1) * 16 + 0;       // +y dependent's -y slot
    int* pYm = inbox + (idx - 1) * 16 + 1;       // -y dependent's +y slot
    int* pZp = inbox + (idx + NTY) * 16 + 2;     // +z dependent's -z slot
    int* pZm = inbox + (idx - NTY) * 16 + 3;     // -z dependent's +z slot

    if (lane == 0 && start > 1) {   // pre-publish: u_{start-1} == u_0 here
        const int pv = start - 1;
        if (ly < NTY - 1) pubp(pYp, pv);
        if (ly > 0)       pubp(pYm, pv);
        if (lz < NTZ - 1) pubp(pZp, pv);
        if (lz > 0)       pubp(pZm, pv);
    }

    const int base0 = ((gz0 + 1) * PPY + (gy + 1)) * PITCH_Y + x0;
    const int base1 = base0 + PITCH_Z;
    const int rowoff = (r == 0) ? -PITCH_Y : PITCH_Y;  // outer y-halo row

    // ---- hoisted flat pointers: A-read set (odd rounds) / B-read set ----
    const float* pAy0 = uA + base0 + rowoff;
    const float* pAy1 = uA + base1 + rowoff;
    const float* pAzm = uA + base0 - PITCH_Z;
    const float* pAzp = uA + base1 + PITCH_Z;
    float*       pBd0 = uB + base0;
    float*       pBd1 = uB + base1;
    const float* pBy0 = uB + base0 + rowoff;
    const float* pBy1 = uB + base1 + rowoff;
    const float* pBzm = uB + base0 - PITCH_Z;
    const float* pBzp = uB + base1 + PITCH_Z;
    float*       pAd0 = uA + base0;
    float*       pAd1 = uA + base1;

    fx4 c0 = *(const fx4*)(uA + base0);
    fx4 c1 = *(const fx4*)(uA + base1);
    const fx4 f0 = *(const fx4*)(fP + base0);
    const fx4 f1 = *(const fx4*)(fP + base1);
    const fx4 ff0 = f0 * f0;
    const fx4 ff1 = f1 * f1;

#define ROUND(I, PY0, PY1, PZM, PZP, PD0, PD1)                                 \
    {                                                                          \
        const int tgt = (I) - 1;                                               \
        const int tYm = (dYm <= (I)) ? tgt : -0x40000000;                      \
        const int tYp = (dYp <= (I)) ? tgt : -0x40000000;                      \
        const int tZm = (dZm <= (I)) ? tgt : -0x40000000;                      \
        const int tZp = (dZp <= (I)) ? tgt : -0x40000000;                      \
        ix4 v;                                                                 \
        for (;;) {                                                             \
            asm volatile("global_load_dwordx4 %0, %1, off sc1\n\t"             \
                         "s_waitcnt vmcnt(0)"                                  \
                         : "=&v"(v) : "v"(inb) : "memory");                    \
            if (v.x >= tYm && v.y >= tYp && v.z >= tZm && v.w >= tZp) break;   \
            const int lag = max(max(tYm - v.x, tYp - v.y),                     \
                                max(tZm - v.z, tZp - v.w));                    \
            if (lag > 2) __builtin_amdgcn_s_sleep(64);                         \
            else         __builtin_amdgcn_s_sleep(16);                         \
        }                                                                      \
        fx4 o0, o1;                                                            \
        o0.x = __shfl_xor(c0.x, 32); o0.y = __shfl_xor(c0.y, 32);              \
        o0.z = __shfl_xor(c0.z, 32); o0.w = __shfl_xor(c0.w, 32);              \
        o1.x = __shfl_xor(c1.x, 32); o1.y = __shfl_xor(c1.y, 32);              \
        o1.z = __shfl_xor(c1.z, 32); o1.w = __shfl_xor(c1.w, 32);              \
        float xm0 = __shfl_up(c0.w, 1);   if (sub == 0)  xm0 = GBIG;           \
        float xp0 = __shfl_down(c0.x, 1); if (sub == 31) xp0 = GBIG;           \
        float xm1 = __shfl_up(c1.w, 1);   if (sub == 0)  xm1 = GBIG;           \
        float xp1 = __shfl_down(c1.x, 1); if (sub == 31) xp1 = GBIG;           \
        if (dmin01 <= (I)) {                                                   \
            fx4 yh0, yh1, zm, zp;                                              \
            asm volatile(                                                      \
                "global_load_dwordx4 %0, %4, off sc1\n\t"                      \
                "global_load_dwordx4 %1, %5, off sc1\n\t"                      \
                "global_load_dwordx4 %2, %6, off sc1\n\t"                      \
                "global_load_dwordx4 %3, %7, off sc1\n\t"                      \
                "s_waitcnt vmcnt(0)"                                           \
                : "=&v"(yh0), "=&v"(yh1), "=&v"(zm), "=&v"(zp)                 \
                : "v"(PY0), "v"(PY1), "v"(PZM), "v"(PZP)                       \
                : "memory");                                                   \
            const fx4 ya0 = (r == 0) ? yh0 : o0;                               \
            const fx4 yb0 = (r == 0) ? o0  : yh0;                              \
            const fx4 ya1 = (r == 0) ? yh1 : o1;                               \
            const fx4 yb1 = (r == 0) ? o1  : yh1;                              \
            fx4 n0, n1;                                                        \
            n0.x = eik_solve(fminf(xm0,  c0.y), fminf(ya0.x, yb0.x),           \
                             fminf(zm.x, c1.x), f0.x, ff0.x, c0.x);            \
            n0.y = eik_solve(fminf(c0.x, c0.z), fminf(ya0.y, yb0.y),           \
                             fminf(zm.y, c1.y), f0.y, ff0.y, c0.y);            \
            n0.z = eik_solve(fminf(c0.y, c0.w), fminf(ya0.z, yb0.z),           \
                             fminf(zm.z, c1.z), f0.z, ff0.z, c0.z);            \
            n0.w = eik_solve(fminf(c0.z, xp0),  fminf(ya0.w, yb0.w),           \
                             fminf(zm.w, c1.w), f0.w, ff0.w, c0.w);            \
            n1.x = eik_solve(fminf(xm1,  c1.y), fminf(ya1.x, yb1.x),           \
                             fminf(c0.x, zp.x), f1.x, ff1.x, c1.x);            \
            n1.y = eik_solve(fminf(c1.x, c1.z), fminf(ya1.y, yb1.y),           \
                             fminf(c0.y, zp.y), f1.y, ff1.y, c1.y);            \
            n1.z = eik_solve(fminf(c1.y, c1.w), fminf(ya1.z, yb1.z),           \
                             fminf(c0.z, zp.z), f1.z, ff1.z, c1.z);            \
            n1.w = eik_solve(fminf(c1.z, xp1),  fminf(ya1.w, yb1.w),           \
                             fminf(c0.w, zp.w), f1.w, ff1.w, c1.w);            \
            if ((I) < NITER) {                                                 \
                if (d0 <= (I)) { c0 = n0; stS(PD0, c0); }                      \
                if (d1 <= (I)) { c1 = n1; stS(PD1, c1); }                      \
            } else {                                                           \
                if (d0 <= (I)) c0 = n0;                                        \
                if (d1 <= (I)) c1 = n1;                                        \
            }                                                                  \
        }                                                                      \
        if ((I) < NITER) {                                                     \
            asm volatile("s_waitcnt vmcnt(0)" ::: "memory");                   \
            if (lane == 0) {                                                   \
                if (ly > 0)       pubp(pYm, (I));                              \
                if (ly < NTY - 1) pubp(pYp, (I));                              \
                if (lz > 0)       pubp(pZm, (I));                              \
                if (lz < NTZ - 1) pubp(pZp, (I));                              \
            }                                                                  \
        }                                                                      \
    }

    int i = start;
    if ((i & 1) == 0) {   // even round reads uB, writes uA
        ROUND(i, pBy0, pBy1, pBzm, pBzp, pAd0, pAd1);
        ++i;
    }
    for (; i <= NITER; i += 2) {
        // odd round: reads uA, writes uB
        ROUND(i, pAy0, pAy1, pAzm, pAzp, pBd0, pBd1);
        if (i + 1 <= NITER) {
            // even round: reads uB, writes uA
            ROUND(i + 1, pBy0, pBy1, pBzm, pBzp, pAd0, pAd1);
        }
    }
#undef ROUND

    // fused extract: compact 128^3 output straight from registers
    float* o = out + (gz0 * GN + gy) * GN + x0;
    *(fx4*)o = c0;
    *(fx4*)(o + GN * GN) = c1;
}

// ---------------------------------------------------------------------------
// fallback path (proven 128-launch structure) if occupancy check fails
// ---------------------------------------------------------------------------
__global__ __launch_bounds__(256) void eik_step(const float* __restrict__ uin,
                                                const float* __restrict__ fP,
                                                float* __restrict__ uout,
                                                int iter) {
    const int lx = threadIdx.x;
    const int gy = blockIdx.y * 8 + threadIdx.y;
    const int gz = blockIdx.z;
    const int x0 = 4 * lx;
    const int dxm = (x0 <= 64 && 64 <= x0 + 3)
                        ? 0
                        : min(abs(x0 - 64), abs(x0 + 3 - 64));
    const int d = dxm + abs(gy - 64) + abs(gz - 64);
    if (d > iter) return;

    const int y = gy + 1;
    const int z = gz + 1;
    const int base = (z * PPY + y) * PITCH_Y + x0;

    const float4 c  = *(const float4*)(uin + base);
    float xm_s = uin[base - 1];
    float xp_s = uin[base + 4];
    if (lx == 0)  xm_s = GBIG;
    if (lx == 31) xp_s = GBIG;
    const float4 ym = *(const float4*)(uin + base - PITCH_Y);
    const float4 yp = *(const float4*)(uin + base + PITCH_Y);
    const float4 zm = *(const float4*)(uin + base - PITCH_Z);
    const float4 zp = *(const float4*)(uin + base + PITCH_Z);
    const float4 f4 = *(const float4*)(fP + base);

    float4 res;
    res.x = eik_solve(fminf(xm_s, c.y), fminf(ym.x, yp.x), fminf(zm.x, zp.x), f4.x, f4.x * f4.x, c.x);
    res.y = eik_solve(fminf(c.x, c.z), fminf(ym.y, yp.y), fminf(zm.y, zp.y), f4.y, f4.y * f4.y, c.y);
    res.z = eik_solve(fminf(c.y, c.w), fminf(ym.z, yp.z), fminf(zm.z, zp.z), f4.z, f4.z * f4.z, c.z);
    res.w = eik_solve(fminf(c.z, xp_s), fminf(ym.w, yp.w), fminf(zm.w, zp.w), f4.w, f4.w * f4.w, c.w);

    *(float4*)(uout + base) = res;
}

__global__ __launch_bounds__(256) void eik_extract(const float* __restrict__ uf,
                                                   float* __restrict__ out) {
    const int j = blockIdx.x * 256 + threadIdx.x;
    const int x4 = j & 31;
    const int y  = (j >> 5) & 127;
    const int z  = j >> 12;
    const float4 v =
        *(const float4*)(uf + ((z + 1) * PPY + (y + 1)) * PITCH_Y + 4 * x4);
    *(float4*)(out + 4 * j) = v;
}

extern "C" void kernel_launch(void* const* d_in, const int* in_sizes, int n_in,
                              void* d_out, int out_size, void* d_ws, size_t ws_size,
                              hipStream_t stream) {
    const float* u0 = (const float*)d_in[0];
    const float* f  = (const float*)d_in[1];
    float* out = (float*)d_out;

    float* uA = (float*)d_ws;                    // 8.65 MB each
    float* uB = uA + PADDED_TOTAL;
    float* fP = uB + PADDED_TOTAL;
    int* inbox = (int*)(fP + PADDED_TOTAL);      // 256 KB wave-tile inbox lines

    {
        const int nb = (PADDED_TOTAL + 255) / 256;
        eik_init<<<nb, 256, 0, stream>>>(u0, f, uA, uB, fP, inbox);
    }

    // Co-residency capacity check (host query, capture-safe, cached):
    // 1024 blocks / 256 CUs -> need >= 4 blocks/CU resident.
    static int resident_ok = -1;
    if (resident_ok < 0) {
        int maxb = 0;
        hipError_t qe =
            hipOccupancyMaxActiveBlocksPerMultiprocessor(&maxb, eik_persist, 256, 0);
        resident_ok = (qe == hipSuccess && maxb >= 4) ? 1 : 0;
    }

    if (resident_ok) {
        eik_persist<<<dim3(1, 32, 32), 256, 0, stream>>>(uA, uB, fP, out, inbox);
        return;
    }

    // fallback: proven 128-launch ping-pong
    const dim3 block(32, 8, 1);
    const dim3 grid(1, 16, 128);
    for (int i = 1; i <= NITER; ++i) {
        const float* in = (i & 1) ? uA : uB;
        float* o        = (i & 1) ? uB : uA;
        eik_step<<<grid, block, 0, stream>>>(in, fP, o, i);
    }
    eik_extract<<<GN * GN * GN / 4 / 256, 256, 0, stream>>>(uA, out);
}